// Round 11
// baseline (999.103 us; speedup 1.0000x reference)
//
#include <hip/hip_runtime.h>

// Sinkhorn EMD, B=8, N=2048, eps=0.005, 50 iters.
// R11: ONE barrier per Sinkhorn iteration (54 total vs 101) via scatter:
// the g-update sum term with fixed-shift M_j = (C1+|g_j|^2-pot_j)/K
// collapses to exp2(x_f(i,j) - L_i_new) = row-normalized plan entry,
// computable inside the f-pass. Each fused iter: stage g (finalize prev
// scatter Sigma redundantly per block), sparse f-gather, scatter plan
// entries into triple-buffered global accumulators (float atomicAdd,
// IC-resident). gpot double-buffered (finalize reads prev parity, owner
// writes current). Builds t={3,15,27,39} dense + scatter over fresh list
// (24-pass cadence validated R7-R10). f potentials never stored globally.
// Invariants kept: IC-coherent atomics/no fences (R6), fully-unrolled
// r-state (R8), online LSE iters 0-2, MARGIN=48/CAP=256 (R9).

#define BB 8
#define NN 2048
#define GRID_BLOCKS 256
#define TPB 1024
#define CAP 256
#define MARGIN 48.0f
#define RPD 8
#define RPS 4

constexpr float EPSV = 0.005f;
constexpr float KS   = EPSV * 0.69314718055994531f; // eps*ln2
constexpr float INVK = 1.0f / KS;
constexpr float C1V  = -EPSV * 7.6246189861593985f; // eps*log(1/2048)
constexpr float C1K  = C1V * INVK;
constexpr float KQ4  = KS * 0.25f;
constexpr float TWOI = 2.0f * INVK;
constexpr float HK   = KS * 0.5f;

__device__ __forceinline__ float fexp2(float x) { return __builtin_amdgcn_exp2f(x); }
__device__ __forceinline__ float flog2(float x) { return __builtin_amdgcn_logf(x); }

__device__ __forceinline__ float cohLoad(const float* p) {
    return __hip_atomic_load(p, __ATOMIC_RELAXED, __HIP_MEMORY_SCOPE_AGENT);
}
__device__ __forceinline__ void cohStore(float* p, float v) {
    __hip_atomic_store(p, v, __ATOMIC_RELAXED, __HIP_MEMORY_SCOPE_AGENT);
}

__device__ __forceinline__ void barrier_sync(int* ctr, int target) {
    __syncthreads();   // drains vmcnt: pot stores + atomics acked at IC
    if (threadIdx.x == 0) {
        __hip_atomic_fetch_add(ctr, 1, __ATOMIC_RELAXED, __HIP_MEMORY_SCOPE_AGENT);
        while (__hip_atomic_load(ctr, __ATOMIC_RELAXED, __HIP_MEMORY_SCOPE_AGENT) < target) {
            __builtin_amdgcn_s_sleep(2);
        }
    }
    __syncthreads();
}

__global__ void __launch_bounds__(TPB, 4) emd_persist(
    const float* __restrict__ preds, const float* __restrict__ gts,
    float* __restrict__ fpot, float* __restrict__ gpot0, float* __restrict__ gpot1,
    float* __restrict__ gacc, float* __restrict__ partials,
    int* __restrict__ bctr, int* __restrict__ gctr, float* __restrict__ out)
{
    __shared__ float4 sjall[2 * NN];       // side0=gts, side1=preds
    __shared__ float  sa[NN];
    __shared__ float  sPrevL[2][64];
    __shared__ float  smS[64][2];
    __shared__ float  smM[64][2];
    __shared__ float  wred[16];
    __shared__ unsigned short slist[64][CAP];   // f-side lists only
    __shared__ unsigned int   scnt[64];

    const int blk  = blockIdx.x;
    const int b    = blk & 7;
    const int rb   = blk >> 3;
    const int wave = threadIdx.x >> 6;
    const int lane = threadIdx.x & 63;
    const int grp  = wave & 7;
    const int half = wave >> 3;
    const int cb   = half << 10;

    const float* pb  = preds + (size_t)b * NN * 3;
    const float* gbp = gts   + (size_t)b * NN * 3;
    float* fb   = fpot  + (size_t)b * NN;
    float* gb0  = gpot0 + (size_t)b * NN;
    float* gb1  = gpot1 + (size_t)b * NN;
    float* accB = gacc  + (size_t)b * NN;        // + buf*BB*NN
    int*   bar  = bctr + b * 32;
    int    bno  = 0;

    for (int t2 = threadIdx.x; t2 < NN; t2 += TPB) {
        float gx = gbp[3*t2], gy = gbp[3*t2+1], gz = gbp[3*t2+2];
        float Gx = gx*TWOI, Gy = gy*TWOI, Gz = gz*TWOI;
        sjall[t2] = make_float4(Gx, Gy, Gz, -KQ4*(Gx*Gx+Gy*Gy+Gz*Gz));
        float qx = pb[3*t2], qy = pb[3*t2+1], qz = pb[3*t2+2];
        float Qx = qx*TWOI, Qy = qy*TWOI, Qz = qz*TWOI;
        sjall[NN+t2] = make_float4(Qx, Qy, Qz, -KQ4*(Qx*Qx+Qy*Qy+Qz*Qz));
    }
    __syncthreads();

    // ---------- online two-phase, passes 0..5 (iters 1..3) ----------
#pragma unroll 1
    for (int pass = 0; pass < 6; ++pass) {
        const int odd = pass & 1;
        const float* pin  = odd ? fb  : gb0;
        float*       pout = odd ? gb0 : fb;
        const int    sjo  = odd ? NN  : 0;
        const int    rso  = odd ? 0   : NN;

        for (int t2 = threadIdx.x; t2 < NN; t2 += TPB)
            sa[t2] = cohLoad(&pin[t2]) * INVK;

        float qx[RPD], qy[RPD], qz[RPD], pc[RPD], s[RPD], m[RPD];
#pragma unroll
        for (int r = 0; r < RPD; ++r) {
            int rl = grp*RPD + r;
            float4 dr = sjall[rso + rb*64 + rl];
            qx[r] = HK*dr.x; qy[r] = HK*dr.y; qz[r] = HK*dr.z;
            pc[r] = C1V - KS*dr.w;
            s[r] = 0.f; m[r] = -1e30f;
        }
        __syncthreads();
#pragma unroll 4
        for (int c = 0; c < 16; ++c) {
            float4 d = sjall[sjo + cb + c*64 + lane];
            float aw = d.w + sa[cb + c*64 + lane];
#pragma unroll
            for (int r = 0; r < RPD; ++r) {
                float x  = fmaf(qx[r], d.x, fmaf(qy[r], d.y, fmaf(qz[r], d.z, aw)));
                float mn = fmaxf(m[r], x);
                s[r] = fmaf(s[r], fexp2(m[r]-mn), fexp2(x-mn));
                m[r] = mn;
            }
        }
#pragma unroll
        for (int r = 0; r < RPD; ++r) {
            float mm = m[r], sv = s[r];
            for (int off = 1; off < 64; off <<= 1) {
                float mo = __shfl_xor(mm, off, 64);
                float so = __shfl_xor(sv, off, 64);
                float mn = fmaxf(mm, mo);
                sv = fmaf(sv, fexp2(mm-mn), so * fexp2(mo-mn));
                mm = mn;
            }
            m[r] = mm; s[r] = sv;
        }
        if (lane == 0) {
#pragma unroll
            for (int r = 0; r < RPD; ++r) {
                smM[grp*RPD + r][half] = m[r];
                smS[grp*RPD + r][half] = s[r];
            }
        }
        __syncthreads();
        if (half == 1 && lane == 0) {
#pragma unroll
            for (int r = 0; r < RPD; ++r) {
                float mo = smM[grp*RPD + r][0], so = smS[grp*RPD + r][0];
                float mn = fmaxf(m[r], mo);
                float st = fmaf(s[r], fexp2(m[r]-mn), so * fexp2(mo-mn));
                float L  = mn + flog2(fmaxf(st, 1e-37f));
                sPrevL[odd][grp*RPD + r] = L;
                cohStore(&pout[rb*64 + grp*RPD + r], pc[r] - KS * L);
            }
        }
        barrier_sync(bar, 32 * (++bno));
    }

    // ---------- fused iterations t=3..49 (one barrier each) ----------
#pragma unroll 1
    for (int t = 3; t < 50; ++t) {
        const bool build = (t == 3) || (t == 15) || (t == 27) || (t == 39);
        float* gpR  = ((t-1) & 1) ? gb1 : gb0;
        float* gpW  = (t & 1) ? gb1 : gb0;
        float* accR = accB + (size_t)((t+2)%3) * BB * NN;
        float* accW = accB + (size_t)(t%3)     * BB * NN;
        float* accZ = accB + (size_t)((t+1)%3) * BB * NN;

        // stage: finalize g^{t-1} from scattered Sigma, owner publishes
        for (int j = threadIdx.x; j < NN; j += TPB) {
            float gw   = sjall[j].w;             // -|g_j|^2 / K
            float prev = cohLoad(&gpR[j]);
            float pot;
            if (t == 3) {
                pot = prev;                      // direct from online phase
            } else {
                float Sig = cohLoad(&accR[j]);
                float Mj  = C1K - gw - prev * INVK;   // = prev log-sum
                float L   = Mj + flog2(fmaxf(Sig, 1e-37f));
                pot = C1V - KS*gw - KS*L;
            }
            sa[j] = pot * INVK;
            if ((j >> 6) == rb) {
                cohStore(&gpW[j], pot);
                cohStore(&accZ[j], 0.0f);        // zero buffer for iter t+1
            }
        }
        if (build && threadIdx.x < 64) scnt[threadIdx.x] = 0;

        if (!build) {
            // ---- sparse fused: wave-autonomous, 4 rows, gather+scatter ----
            float qx[RPS], qy[RPS], qz[RPS], M4[RPS], Lr[RPS];
#pragma unroll
            for (int r = 0; r < RPS; ++r) {
                int rl = wave*RPS + r;
                float4 dr = sjall[NN + rb*64 + rl];
                qx[r] = HK*dr.x; qy[r] = HK*dr.y; qz[r] = HK*dr.z;
                M4[r] = sPrevL[0][rl];
            }
            __syncthreads();                     // sa ready
#pragma unroll
            for (int r = 0; r < RPS; ++r) {
                const int rl = wave*RPS + r;
                const unsigned int cnt = scnt[rl];
                float s1 = 0.f;
                if (cnt <= CAP) {
#pragma unroll 1
                    for (unsigned int k = lane; k < cnt; k += 64) {
                        int j = slist[rl][k];
                        float4 d = sjall[j];
                        float x = fmaf(qx[r], d.x, fmaf(qy[r], d.y,
                                  fmaf(qz[r], d.z, d.w + sa[j])));
                        s1 += fexp2(fminf(x - M4[r], 100.f));
                    }
                } else {
#pragma unroll 1
                    for (int c = 0; c < 32; ++c) {
                        int j = c*64 + lane;
                        float4 d = sjall[j];
                        float x = fmaf(qx[r], d.x, fmaf(qy[r], d.y,
                                  fmaf(qz[r], d.z, d.w + sa[j])));
                        s1 += fexp2(fminf(x - M4[r], 100.f));
                    }
                }
                for (int off = 1; off < 64; off <<= 1) s1 += __shfl_xor(s1, off, 64);
                Lr[r] = M4[r] + flog2(fmaxf(s1, 1e-37f));
            }
            if (lane == 0) {
#pragma unroll
                for (int r = 0; r < RPS; ++r) sPrevL[0][wave*RPS + r] = Lr[r];
            }
            // scatter row-normalized plan entries into accW
#pragma unroll
            for (int r = 0; r < RPS; ++r) {
                const int rl = wave*RPS + r;
                const unsigned int cnt = scnt[rl];
                if (cnt <= CAP) {
#pragma unroll 1
                    for (unsigned int k = lane; k < cnt; k += 64) {
                        int j = slist[rl][k];
                        float4 d = sjall[j];
                        float x = fmaf(qx[r], d.x, fmaf(qy[r], d.y,
                                  fmaf(qz[r], d.z, d.w + sa[j])));
                        atomicAdd(&accW[j], fexp2(fminf(x - Lr[r], 100.f)));
                    }
                } else {
#pragma unroll 1
                    for (int c = 0; c < 32; ++c) {
                        int j = c*64 + lane;
                        float4 d = sjall[j];
                        float x = fmaf(qx[r], d.x, fmaf(qy[r], d.y,
                                  fmaf(qz[r], d.z, d.w + sa[j])));
                        atomicAdd(&accW[j], fexp2(fminf(x - Lr[r], 100.f)));
                    }
                }
            }
        } else {
            // ---- build fused: dense sweep + compaction, then scatter ----
            float qx[RPD], qy[RPD], qz[RPD], M[RPD], s[RPD], Lr[RPD];
#pragma unroll
            for (int r = 0; r < RPD; ++r) {
                int rl = grp*RPD + r;
                float4 dr = sjall[NN + rb*64 + rl];
                qx[r] = HK*dr.x; qy[r] = HK*dr.y; qz[r] = HK*dr.z;
                M[r] = sPrevL[0][rl];
                s[r] = 0.f;
            }
            __syncthreads();                     // sa + scnt ready
#pragma unroll
            for (int r = 0; r < RPD; ++r) {
                const int rl = grp*RPD + r;
                const float thr = M[r] - MARGIN;
                float s1 = 0.f;
#pragma unroll 1
                for (int c = 0; c < 16; ++c) {
                    int j = cb + c*64 + lane;
                    float4 d = sjall[j];
                    float x = fmaf(qx[r], d.x, fmaf(qy[r], d.y,
                              fmaf(qz[r], d.z, d.w + sa[j])));
                    s1 += fexp2(fminf(x - M[r], 100.f));
                    bool pred = (x >= thr);
                    unsigned long long mask = __ballot((int)pred);
                    int npop = __popcll(mask);
                    unsigned int base = 0;
                    if (lane == 0 && npop)
                        base = atomicAdd(&scnt[rl], (unsigned)npop);
                    base = (unsigned)__shfl((int)base, 0, 64);
                    if (pred) {
                        unsigned int pos = base + __popcll(mask & ((1ull << lane) - 1ull));
                        if (pos < CAP) slist[rl][pos] = (unsigned short)j;
                    }
                }
                for (int off = 1; off < 64; off <<= 1) s1 += __shfl_xor(s1, off, 64);
                s[r] = s1;
            }
            if (lane == 0) {
#pragma unroll
                for (int r = 0; r < RPD; ++r) smS[grp*RPD + r][half] = s[r];
            }
            __syncthreads();
#pragma unroll
            for (int r = 0; r < RPD; ++r) {      // both halves derive L
                int rl = grp*RPD + r;
                float st = smS[rl][0] + smS[rl][1];
                Lr[r] = M[r] + flog2(fmaxf(st, 1e-37f));
            }
            if (half == 1 && lane == 0) {
#pragma unroll
                for (int r = 0; r < RPD; ++r) sPrevL[0][grp*RPD + r] = Lr[r];
            }
            // scatter over the fresh list (halves split the list)
#pragma unroll
            for (int r = 0; r < RPD; ++r) {
                const int rl = grp*RPD + r;
                const unsigned int cnt = scnt[rl];
                if (cnt <= CAP) {
#pragma unroll 1
                    for (unsigned int k = (half << 6) + lane; k < cnt; k += 128) {
                        int j = slist[rl][k];
                        float4 d = sjall[j];
                        float x = fmaf(qx[r], d.x, fmaf(qy[r], d.y,
                                  fmaf(qz[r], d.z, d.w + sa[j])));
                        atomicAdd(&accW[j], fexp2(fminf(x - Lr[r], 100.f)));
                    }
                } else {
#pragma unroll 1
                    for (int c = 0; c < 16; ++c) {
                        int j = cb + c*64 + lane;
                        float4 d = sjall[j];
                        float x = fmaf(qx[r], d.x, fmaf(qy[r], d.y,
                                  fmaf(qz[r], d.z, d.w + sa[j])));
                        atomicAdd(&accW[j], fexp2(fminf(x - Lr[r], 100.f)));
                    }
                }
            }
        }
        barrier_sync(bar, 32 * (++bno));
    }

    // ---------- dis: finalize g^50, then sum P*C over f-lists ----------
    {
        float* gpR  = gb1;                               // (50-1)&1 = 1
        float* accR = accB + (size_t)(1) * BB * NN;      // (50+2)%3 = 1
        for (int j = threadIdx.x; j < NN; j += TPB) {
            float gw   = sjall[j].w;
            float prev = cohLoad(&gpR[j]);
            float Sig  = cohLoad(&accR[j]);
            float Mj   = C1K - gw - prev * INVK;
            float L    = Mj + flog2(fmaxf(Sig, 1e-37f));
            sa[j] = (C1V - KS*gw - KS*L) * INVK;
        }
        float qx[RPS], qy[RPS], qz[RPS], pn4[RPS], bb2[RPS], acc[RPS];
#pragma unroll
        for (int r = 0; r < RPS; ++r) {
            int rl = wave*RPS + r;
            float4 dr = sjall[NN + rb*64 + rl];
            qx[r] = HK*dr.x; qy[r] = HK*dr.y; qz[r] = HK*dr.z;
            pn4[r] = -KS*dr.w;
            bb2[r] = C1K - sPrevL[0][rl];
            acc[r] = 0.f;
        }
        __syncthreads();
#pragma unroll
        for (int r = 0; r < RPS; ++r) {
            const int rl = wave*RPS + r;
            const unsigned int cnt = scnt[rl];
            float aa = 0.f;
            if (cnt <= CAP) {
#pragma unroll 1
                for (unsigned int k = lane; k < cnt; k += 64) {
                    int j = slist[rl][k];
                    float4 d = sjall[j];
                    float dot = fmaf(qx[r], d.x, fmaf(qy[r], d.y, qz[r]*d.z));
                    float y   = dot + d.w + sa[j] + bb2[r];
                    float e   = fexp2(fminf(y, 80.f));
                    aa = fmaf(e, fmaf(-KS, dot, pn4[r] - KS*d.w), aa);
                }
            } else {
#pragma unroll 1
                for (int c = 0; c < 32; ++c) {
                    int j = c*64 + lane;
                    float4 d = sjall[j];
                    float dot = fmaf(qx[r], d.x, fmaf(qy[r], d.y, qz[r]*d.z));
                    float y   = dot + d.w + sa[j] + bb2[r];
                    float e   = fexp2(fminf(y, 80.f));
                    aa = fmaf(e, fmaf(-KS, dot, pn4[r] - KS*d.w), aa);
                }
            }
            acc[r] = aa;
        }
        float tot = acc[0] + acc[1] + acc[2] + acc[3];
        for (int off = 1; off < 64; off <<= 1) tot += __shfl_xor(tot, off, 64);
        if (lane == 0) wred[wave] = tot;
        __syncthreads();
        if (threadIdx.x == 0) {
            float v = 0.f;
            for (int w = 0; w < 16; ++w) v += wred[w];
            cohStore(&partials[blk], v);
        }
    }

    barrier_sync(gctr, GRID_BLOCKS);

    if (blk == 0) {
        float v = (threadIdx.x < GRID_BLOCKS) ? cohLoad(&partials[threadIdx.x]) : 0.f;
        for (int off = 1; off < 64; off <<= 1) v += __shfl_xor(v, off, 64);
        if (lane == 0) wred[wave] = v;
        __syncthreads();
        if (threadIdx.x == 0) {
            float t2 = 0.f;
            for (int w = 0; w < 16; ++w) t2 += wred[w];
            out[0] = t2 * (1.0f / BB);
        }
    }
}

extern "C" void kernel_launch(void* const* d_in, const int* in_sizes, int n_in,
                              void* d_out, int out_size, void* d_ws, size_t ws_size,
                              hipStream_t stream) {
    const float* preds = (const float*)d_in[0];
    const float* gts   = (const float*)d_in[1];
    float* fp       = (float*)d_ws;                    // [B*N]
    float* gp0      = fp  + BB * NN;                   // [B*N]
    float* gp1      = gp0 + BB * NN;                   // [B*N]
    float* gacc     = gp1 + BB * NN;                   // [3][B*N]
    float* partials = gacc + 3 * BB * NN;              // [256]
    int*   bctr     = (int*)(partials + GRID_BLOCKS);  // 8 x 32
    int*   gctr     = bctr + BB * 32;                  // [32]
    float* out      = (float*)d_out;

    size_t zbytes = (size_t)(6 * BB * NN + GRID_BLOCKS) * sizeof(float)
                  + (size_t)(BB * 32 + 32) * sizeof(int);
    hipMemsetAsync(d_ws, 0, zbytes, stream);

    emd_persist<<<dim3(GRID_BLOCKS), dim3(TPB), 0, stream>>>(
        preds, gts, fp, gp0, gp1, gacc, partials, bctr, gctr, out);
}

// Round 12
// 604.194 us; speedup vs baseline: 1.6536x; 1.6536x over previous
//
#include <hip/hip_runtime.h>

// Sinkhorn EMD, B=8, N=2048, eps=0.005, 50 iters.
// R12 = R10 structure (gather-only, IC-coherent, per-batch monotonic
// barriers) with the sparse-pass serial chain shortened:
//  - sparse passes read pot[j] directly per candidate (no sa staging,
//    no intra-pass __syncthreads)
//  - wave<->4-rows fixed binding; row constants / Lprev / list counts in
//    REGISTERS across all passes (no sPrevL/pair-merge LDS round trips)
//  - dense/online/build keep sa staging (full sweep) with same mapping.
// R11's scatter fusion reverted (atomic traffic 411MB >> barrier savings).
// Invariants: IC atomics no fences (R6), unrolled r-state (R8),
// online 0-5, builds {6,7}+24k, MARGIN=48, CAP=256 (R9/R10, absmax 0.0).

#define BB 8
#define NN 2048
#define NPASS 100
#define ONLINE_PASSES 6
#define RPW 4
#define GRID_BLOCKS 256
#define BLOCKS_PER_BATCH 32
#define TPB 1024
#define CAP 256
#define MARGIN 48.0f

constexpr float EPSV = 0.005f;
constexpr float KS   = EPSV * 0.69314718055994531f; // eps*ln2
constexpr float INVK = 1.0f / KS;
constexpr float C1V  = -EPSV * 7.6246189861593985f; // eps*log(1/2048)
constexpr float C1K  = C1V * INVK;
constexpr float KQ4  = KS * 0.25f;
constexpr float TWOI = 2.0f * INVK;
constexpr float HK   = KS * 0.5f;

__device__ __forceinline__ float fexp2(float x) { return __builtin_amdgcn_exp2f(x); }
__device__ __forceinline__ float flog2(float x) { return __builtin_amdgcn_logf(x); }

__device__ __forceinline__ float cohLoad(const float* p) {
    return __hip_atomic_load(p, __ATOMIC_RELAXED, __HIP_MEMORY_SCOPE_AGENT);
}
__device__ __forceinline__ void cohStore(float* p, float v) {
    __hip_atomic_store(p, v, __ATOMIC_RELAXED, __HIP_MEMORY_SCOPE_AGENT);
}

__device__ __forceinline__ void barrier_sync(int* ctr, int target) {
    __syncthreads();   // drains vmcnt: all waves' cohStores acked at IC
    if (threadIdx.x == 0) {
        __hip_atomic_fetch_add(ctr, 1, __ATOMIC_RELAXED, __HIP_MEMORY_SCOPE_AGENT);
        while (__hip_atomic_load(ctr, __ATOMIC_RELAXED, __HIP_MEMORY_SCOPE_AGENT) < target) {
            __builtin_amdgcn_s_sleep(1);
        }
    }
    __syncthreads();
}

__global__ void __launch_bounds__(TPB, 4) emd_persist(
    const float* __restrict__ preds, const float* __restrict__ gts,
    float* __restrict__ fpot, float* __restrict__ gpot,
    float* __restrict__ partials, int* __restrict__ bctr, int* __restrict__ gctr,
    float* __restrict__ out)
{
    __shared__ float4 sjall[2 * NN];          // side0=gts, side1=preds
    __shared__ float  sa[NN];                 // staged pots (dense passes only)
    __shared__ float  wred[16];
    __shared__ unsigned short slist[2][64][CAP];

    const int blk  = blockIdx.x;
    const int b    = blk & 7;
    const int rb   = blk >> 3;
    const int wave = threadIdx.x >> 6;
    const int lane = threadIdx.x & 63;
    const int rowL0 = wave * RPW;             // 0..60
    const int row0  = rb * 64 + rowL0;        // global row base for this wave

    const float* pb  = preds + (size_t)b * NN * 3;
    const float* gbp = gts   + (size_t)b * NN * 3;
    float* fb = fpot + (size_t)b * NN;
    float* gb = gpot + (size_t)b * NN;
    int*   bar = bctr + b * 32;

    for (int t = threadIdx.x; t < NN; t += TPB) {
        float gx = gbp[3*t], gy = gbp[3*t+1], gz = gbp[3*t+2];
        float Gx = gx*TWOI, Gy = gy*TWOI, Gz = gz*TWOI;
        sjall[t] = make_float4(Gx, Gy, Gz, -KQ4*(Gx*Gx+Gy*Gy+Gz*Gz));
        float qx = pb[3*t], qy = pb[3*t+1], qz = pb[3*t+2];
        float Qx = qx*TWOI, Qy = qy*TWOI, Qz = qz*TWOI;
        sjall[NN+t] = make_float4(Qx, Qy, Qz, -KQ4*(Qx*Qx+Qy*Qy+Qz*Qz));
    }
    __syncthreads();

    // wave-resident row constants, both sides (loaded ONCE)
    float qxf[RPW], qyf[RPW], qzf[RPW], pcf[RPW];
    float qxg[RPW], qyg[RPW], qzg[RPW], pcg[RPW];
#pragma unroll
    for (int r = 0; r < RPW; ++r) {
        float4 df = sjall[NN + row0 + r];     // preds rows (f side)
        qxf[r] = HK*df.x; qyf[r] = HK*df.y; qzf[r] = HK*df.z;
        pcf[r] = C1V - KS*df.w;
        float4 dg = sjall[row0 + r];          // gts rows (g side)
        qxg[r] = HK*dg.x; qyg[r] = HK*dg.y; qzg[r] = HK*dg.z;
        pcg[r] = C1V - KS*dg.w;
    }
    float LpF[RPW] = {0,0,0,0}, LpG[RPW] = {0,0,0,0};
    int   cnF[RPW] = {0,0,0,0}, cnG[RPW] = {0,0,0,0};

#pragma unroll 1
    for (int pass = 0; pass < NPASS; ++pass) {
        const int odd = pass & 1;
        const int colOff = odd ? NN : 0;
        const float* pin  = odd ? fb : gb;
        float*       pout = odd ? gb : fb;
        const bool isBuild  = (pass >= ONLINE_PASSES) &&
                              (((pass - ONLINE_PASSES) % 24) < 2);
        const bool isSparse = (pass >= ONLINE_PASSES) && !isBuild;

        float qx[RPW], qy[RPW], qz[RPW], pc[RPW], M[RPW];
#pragma unroll
        for (int r = 0; r < RPW; ++r) {
            qx[r] = odd ? qxg[r] : qxf[r];
            qy[r] = odd ? qyg[r] : qyf[r];
            qz[r] = odd ? qzg[r] : qzf[r];
            pc[r] = odd ? pcg[r] : pcf[r];
            M[r]  = odd ? LpG[r] : LpF[r];
        }

        if (isSparse) {
            // ---- sparse: no staging, no intra-pass sync ----
            float L[RPW];
#pragma unroll
            for (int r = 0; r < RPW; ++r) {
                const int cnt = odd ? cnG[r] : cnF[r];
                const unsigned short* lb = slist[odd][rowL0 + r];
                float s1 = 0.f;
                if (cnt <= CAP) {
#pragma unroll 1
                    for (int k = lane; k < cnt; k += 64) {
                        int j = lb[k];
                        float4 d = sjall[colOff + j];
                        float aw = fmaf(cohLoad(&pin[j]), INVK, d.w);
                        float x  = fmaf(qx[r], d.x, fmaf(qy[r], d.y, fmaf(qz[r], d.z, aw)));
                        s1 += fexp2(fminf(x - M[r], 100.f));
                    }
                } else {
#pragma unroll 1
                    for (int c = 0; c < 32; ++c) {
                        int j = c*64 + lane;
                        float4 d = sjall[colOff + j];
                        float aw = fmaf(cohLoad(&pin[j]), INVK, d.w);
                        float x  = fmaf(qx[r], d.x, fmaf(qy[r], d.y, fmaf(qz[r], d.z, aw)));
                        s1 += fexp2(fminf(x - M[r], 100.f));
                    }
                }
                for (int off = 1; off < 64; off <<= 1) s1 += __shfl_xor(s1, off, 64);
                L[r] = M[r] + flog2(fmaxf(s1, 1e-37f));
            }
#pragma unroll
            for (int r = 0; r < RPW; ++r) {
                if (odd) LpG[r] = L[r]; else LpF[r] = L[r];
                if (lane == 0) cohStore(&pout[row0 + r], pc[r] - KS * L[r]);
            }
        } else {
            // ---- dense-type: stage sa, full sweep ----
            for (int t = threadIdx.x; t < NN; t += TPB)
                sa[t] = cohLoad(&pin[t]) * INVK;
            __syncthreads();

            if (pass < ONLINE_PASSES) {
                float m[RPW], s[RPW];
#pragma unroll
                for (int r = 0; r < RPW; ++r) { m[r] = -1e30f; s[r] = 0.f; }
#pragma unroll 2
                for (int c = 0; c < 32; ++c) {
                    float4 d = sjall[colOff + c*64 + lane];
                    float aw = d.w + sa[c*64 + lane];
#pragma unroll
                    for (int r = 0; r < RPW; ++r) {
                        float x  = fmaf(qx[r], d.x, fmaf(qy[r], d.y, fmaf(qz[r], d.z, aw)));
                        float mn = fmaxf(m[r], x);
                        s[r] = fmaf(s[r], fexp2(m[r]-mn), fexp2(x-mn));
                        m[r] = mn;
                    }
                }
#pragma unroll
                for (int r = 0; r < RPW; ++r) {
                    float mm = m[r], sv = s[r];
                    for (int off = 1; off < 64; off <<= 1) {
                        float mo = __shfl_xor(mm, off, 64);
                        float so = __shfl_xor(sv, off, 64);
                        float mn = fmaxf(mm, mo);
                        sv = fmaf(sv, fexp2(mm-mn), so * fexp2(mo-mn));
                        mm = mn;
                    }
                    float L = mm + flog2(fmaxf(sv, 1e-37f));
                    if (odd) LpG[r] = L; else LpF[r] = L;
                    if (lane == 0) cohStore(&pout[row0 + r], pc[r] - KS * L);
                }
            } else {
                // build: dense fixed-shift + register-count compaction
                float s[RPW]; int cn[RPW];
#pragma unroll
                for (int r = 0; r < RPW; ++r) { s[r] = 0.f; cn[r] = 0; }
#pragma unroll 1
                for (int c = 0; c < 32; ++c) {
                    int j = c*64 + lane;
                    float4 d = sjall[colOff + j];
                    float aw = d.w + sa[j];
#pragma unroll
                    for (int r = 0; r < RPW; ++r) {
                        float x = fmaf(qx[r], d.x, fmaf(qy[r], d.y, fmaf(qz[r], d.z, aw)));
                        s[r] += fexp2(fminf(x - M[r], 100.f));
                        bool pred = (x >= M[r] - MARGIN);
                        unsigned long long mask = __ballot((int)pred);
                        if (pred) {
                            int pos = cn[r] + __popcll(mask & ((1ull << lane) - 1ull));
                            if (pos < CAP) slist[odd][rowL0 + r][pos] = (unsigned short)j;
                        }
                        cn[r] += __popcll(mask);   // wave-uniform
                    }
                }
#pragma unroll
                for (int r = 0; r < RPW; ++r) {
                    float sv = s[r];
                    for (int off = 1; off < 64; off <<= 1) sv += __shfl_xor(sv, off, 64);
                    float L = M[r] + flog2(fmaxf(sv, 1e-37f));
                    if (odd) { LpG[r] = L; cnG[r] = cn[r]; }
                    else     { LpF[r] = L; cnF[r] = cn[r]; }
                    if (lane == 0) cohStore(&pout[row0 + r], pc[r] - KS * L);
                }
            }
        }
        barrier_sync(bar, BLOCKS_PER_BATCH * (pass + 1));
    }

    // ---- dis: sum P*C over f-lists (side 0), direct pot loads ----
    {
        float acc[RPW];
#pragma unroll
        for (int r = 0; r < RPW; ++r) acc[r] = 0.f;
#pragma unroll
        for (int r = 0; r < RPW; ++r) {
            const int cnt = cnF[r];
            const unsigned short* lb = slist[0][rowL0 + r];
            const float bb2 = C1K - LpF[r];
            const float pn  = pcf[r] - C1V;    // |p|^2
            float aa = 0.f;
            if (cnt <= CAP) {
#pragma unroll 1
                for (int k = lane; k < cnt; k += 64) {
                    int j = lb[k];
                    float4 d = sjall[j];
                    float aw = fmaf(cohLoad(&gb[j]), INVK, d.w);
                    float dot = fmaf(qxf[r], d.x, fmaf(qyf[r], d.y, qzf[r]*d.z));
                    float y   = dot + aw + bb2;
                    float e   = fexp2(fminf(y, 80.f));
                    aa = fmaf(e, fmaf(-KS, dot, pn - KS*d.w), aa);
                }
            } else {
#pragma unroll 1
                for (int c = 0; c < 32; ++c) {
                    int j = c*64 + lane;
                    float4 d = sjall[j];
                    float aw = fmaf(cohLoad(&gb[j]), INVK, d.w);
                    float dot = fmaf(qxf[r], d.x, fmaf(qyf[r], d.y, qzf[r]*d.z));
                    float y   = dot + aw + bb2;
                    float e   = fexp2(fminf(y, 80.f));
                    aa = fmaf(e, fmaf(-KS, dot, pn - KS*d.w), aa);
                }
            }
            acc[r] = aa;
        }
        float tot = acc[0] + acc[1] + acc[2] + acc[3];
        for (int off = 1; off < 64; off <<= 1) tot += __shfl_xor(tot, off, 64);
        if (lane == 0) wred[wave] = tot;
        __syncthreads();
        if (threadIdx.x == 0) {
            float v = 0.f;
            for (int w = 0; w < 16; ++w) v += wred[w];
            cohStore(&partials[blk], v);
        }
    }

    barrier_sync(gctr, GRID_BLOCKS);

    if (blk == 0) {
        float v = (threadIdx.x < GRID_BLOCKS) ? cohLoad(&partials[threadIdx.x]) : 0.f;
        for (int off = 1; off < 64; off <<= 1) v += __shfl_xor(v, off, 64);
        if (lane == 0) wred[wave] = v;
        __syncthreads();
        if (threadIdx.x == 0) {
            float t2 = 0.f;
            for (int w = 0; w < 16; ++w) t2 += wred[w];
            out[0] = t2 * (1.0f / BB);
        }
    }
}

extern "C" void kernel_launch(void* const* d_in, const int* in_sizes, int n_in,
                              void* d_out, int out_size, void* d_ws, size_t ws_size,
                              hipStream_t stream) {
    const float* preds = (const float*)d_in[0];
    const float* gts   = (const float*)d_in[1];
    float* fp       = (float*)d_ws;
    float* gp       = fp + BB * NN;
    float* partials = gp + BB * NN;
    int*   bctr     = (int*)(partials + GRID_BLOCKS);
    int*   gctr     = bctr + BB * 32;
    float* out      = (float*)d_out;

    size_t zbytes = (size_t)(2 * BB * NN + GRID_BLOCKS) * sizeof(float)
                  + (size_t)(BB * 32 + 32) * sizeof(int);
    hipMemsetAsync(d_ws, 0, zbytes, stream);

    emd_persist<<<dim3(GRID_BLOCKS), dim3(TPB), 0, stream>>>(
        preds, gts, fp, gp, partials, bctr, gctr, out);
}